// Round 17
// baseline (357.813 us; speedup 1.0000x reference)
//
#include <hip/hip_runtime.h>
#include <hip/hip_bf16.h>
#include <math.h>

// Sizes (fixed by the problem)
#define B 64
#define T 64
#define E_ENC 1024
#define EMB 512
#define D 512
#define L 32
#define S 31
#define A 512
#define V 30000
#define KSZ 7
#define KC (D * KSZ)   // 3584 = conv GEMM K

typedef __attribute__((ext_vector_type(8))) short bf16x8;
typedef __attribute__((ext_vector_type(4))) float f32x4;

__device__ __forceinline__ unsigned short f2bf(float f) {
  union { float f; unsigned int u; } x; x.f = f;
  unsigned int r = (x.u + 0x7fffu + ((x.u >> 16) & 1u)) >> 16;
  return (unsigned short)r;
}

__device__ __forceinline__ void gload_lds16(const void* g, void* l) {
  __builtin_amdgcn_global_load_lds(
      (const __attribute__((address_space(1))) unsigned int*)g,
      (__attribute__((address_space(3))) unsigned int*)l, 16, 0, 0);
}

// ---------------------------------------------------------------------------
// wv[e] = sum_a Wp[a]*Wenc[a,e];  c0 = sum_a benc[a]*Wp[a]
__global__ void k_wv(const float* __restrict__ Wenc, const float* __restrict__ Wp,
                     const float* __restrict__ benc, float* __restrict__ wv,
                     float* __restrict__ c0) {
  __shared__ float sp[4][64];
  __shared__ float red[256];
  int el = threadIdx.x & 63, part = threadIdx.x >> 6;
  int e = blockIdx.x * 64 + el;
  float s = 0.f;
  for (int a = part * 128; a < part * 128 + 128; ++a)
    s += Wp[a] * Wenc[(size_t)a * E_ENC + e];
  sp[part][el] = s;
  __syncthreads();
  if (part == 0) wv[e] = sp[0][el] + sp[1][el] + sp[2][el] + sp[3][el];
  if (blockIdx.x == 0) {
    int t = threadIdx.x;
    float v = Wp[t] * benc[t] + Wp[t + 256] * benc[t + 256];
    red[t] = v;
    __syncthreads();
    for (int off = 128; off > 0; off >>= 1) {
      if (t < off) red[t] += red[t + off];
      __syncthreads();
    }
    if (t == 0) c0[0] = red[0];
  }
}

// ---------------------------------------------------------------------------
// Per-b: enc_mean (bf16), fscore -> softmax over t -> ctx (bf16)
__global__ void k_mean_ctx(const float* __restrict__ features, const float* __restrict__ wv,
                           const float* __restrict__ c0, unsigned short* __restrict__ enc_meanb,
                           unsigned short* __restrict__ ctxb) {
  int b = blockIdx.x, tid = threadIdx.x;
  const float* fb = features + (size_t)b * T * E_ENC;
  __shared__ float s_attw[T];

  float m0 = 0, m1 = 0, m2 = 0, m3 = 0;
  for (int t = 0; t < T; ++t) {
    const float* r = fb + t * E_ENC;
    m0 += r[tid]; m1 += r[tid + 256]; m2 += r[tid + 512]; m3 += r[tid + 768];
  }
  size_t eb = (size_t)b * E_ENC;
  enc_meanb[eb + tid]       = f2bf(m0 * (1.f / 64.f));
  enc_meanb[eb + tid + 256] = f2bf(m1 * (1.f / 64.f));
  enc_meanb[eb + tid + 512] = f2bf(m2 * (1.f / 64.f));
  enc_meanb[eb + tid + 768] = f2bf(m3 * (1.f / 64.f));

  {
    int t = tid >> 2, part = tid & 3;
    const float* r = fb + t * E_ENC + part * 256;
    const float* wp = wv + part * 256;
    float s = 0.f;
    for (int e = 0; e < 256; e += 4) {
      float4 f4 = *(const float4*)(r + e);
      float4 w4 = *(const float4*)(wp + e);
      s += f4.x * w4.x + f4.y * w4.y + f4.z * w4.z + f4.w * w4.w;
    }
    s += __shfl_xor(s, 1);
    s += __shfl_xor(s, 2);
    if (part == 0) s_attw[t] = s + c0[0];
  }
  __syncthreads();
  if (tid < 64) {
    float v = s_attw[tid];
    float mx = v;
    #pragma unroll
    for (int off = 32; off > 0; off >>= 1) mx = fmaxf(mx, __shfl_xor(mx, off));
    float e = expf(v - mx);
    float sm = e;
    #pragma unroll
    for (int off = 32; off > 0; off >>= 1) sm += __shfl_xor(sm, off);
    s_attw[tid] = e / sm;
  }
  __syncthreads();
  float ca = 0, cb = 0, cc = 0, cd = 0;
  for (int t = 0; t < T; ++t) {
    float w = s_attw[t];
    const float* r = fb + t * E_ENC;
    ca += w * r[tid]; cb += w * r[tid + 256]; cc += w * r[tid + 512]; cd += w * r[tid + 768];
  }
  ctxb[eb + tid]       = f2bf(ca);
  ctxb[eb + tid + 256] = f2bf(cb);
  ctxb[eb + tid + 512] = f2bf(cc);
  ctxb[eb + tid + 768] = f2bf(cd);
}

// ---------------------------------------------------------------------------
// Gather embedding rows per caption token -> bf16 Xe[2048][512]
__global__ void k_gather_emb(const float* __restrict__ embed_W,
                             const int* __restrict__ captions,
                             unsigned short* __restrict__ Xe) {
  int g = blockIdx.x, tid = threadIdx.x;
  int cap = captions[g];
  const float* src = embed_W + (size_t)cap * EMB;
  float2 v = *(const float2*)(src + tid * 2);
  unsigned int pk = (unsigned int)f2bf(v.x) | ((unsigned int)f2bf(v.y) << 16);
  *(unsigned int*)(Xe + (size_t)g * EMB + tid * 2) = pk;
}

// Full W1 conversion: w1b[d][k] = bf16(W1[d][k])
__global__ void k_cvt_w1(const float* __restrict__ W1, unsigned short* __restrict__ w1b) {
  int d = blockIdx.x, tid = threadIdx.x;
  #pragma unroll
  for (int i = 0; i < 3; ++i) {
    int c = tid * 2 + i * 512;
    float2 v = *(const float2*)(W1 + (size_t)d * (E_ENC + EMB) + c);
    unsigned int pk = (unsigned int)f2bf(v.x) | ((unsigned int)f2bf(v.y) << 16);
    *(unsigned int*)(w1b + (size_t)d * (E_ENC + EMB) + c) = pk;
  }
}

// ---------------------------------------------------------------------------
// Fused x1 GEMM: x1[g][d] = b1[d] + [enc_mean(b)||emb(g)] . w1b[d,:]
__global__ __launch_bounds__(256) void k_x1f_mfma(
    const unsigned short* __restrict__ enc_meanb,  // [64][1024] bf16
    const unsigned short* __restrict__ Xe,         // [2048][512] bf16
    const unsigned short* __restrict__ w1b,        // [512][1536] bf16
    const float* __restrict__ b1, float* __restrict__ x1) {
  __shared__ __align__(16) unsigned short As[64 * 64];  // 8 KB
  __shared__ __align__(16) unsigned short Bs[64 * 64];  // 8 KB
  int c0 = blockIdx.x * 64, g0 = blockIdx.y * 64;
  int tid = threadIdx.x, lane = tid & 63, wave = tid >> 6;
  int wr = wave >> 1, wc = wave & 1;
  int rsel = lane & 15, hi = lane >> 4;

  f32x4 acc[2][2];
  #pragma unroll
  for (int m = 0; m < 2; ++m)
    #pragma unroll
    for (int n = 0; n < 2; ++n) acc[m][n] = (f32x4){0.f, 0.f, 0.f, 0.f};

  int r1 = tid >> 3, s1 = tid & 7;
  int sw = (s1 ^ (r1 & 7)) * 8;
  const unsigned short* emA1 = enc_meanb + (size_t)(g0 >> 5) * 1024 + sw;
  const unsigned short* emA2 = enc_meanb + (size_t)((g0 >> 5) + 1) * 1024 + sw;
  const unsigned short* xeA1 = Xe + (size_t)(g0 + r1) * 512 + sw;
  const unsigned short* xeA2 = Xe + (size_t)(g0 + r1 + 32) * 512 + sw;
  const unsigned short* gB1 = w1b + (size_t)(c0 + r1) * (E_ENC + EMB) + sw;
  const unsigned short* gB2 = w1b + (size_t)(c0 + r1 + 32) * (E_ENC + EMB) + sw;
  unsigned short* aD1 = As + wave * 512;
  unsigned short* aD2 = As + 2048 + wave * 512;
  unsigned short* bD1 = Bs + wave * 512;
  unsigned short* bD2 = Bs + 2048 + wave * 512;

  int slot0 = hi ^ (rsel & 7);
  int slot1 = (4 + hi) ^ (rsel & 7);

  for (int kt = 0; kt < 24; ++kt) {
    const unsigned short *pA1, *pA2;
    if (kt < 16) { pA1 = emA1 + kt * 64; pA2 = emA2 + kt * 64; }
    else         { pA1 = xeA1 + (kt - 16) * 64; pA2 = xeA2 + (kt - 16) * 64; }
    gload_lds16(pA1, aD1);
    gload_lds16(pA2, aD2);
    gload_lds16(gB1, bD1);
    gload_lds16(gB2, bD2);
    gB1 += 64; gB2 += 64;
    __syncthreads();

    bf16x8 af[2][2], bfr[2][2];
    #pragma unroll
    for (int m = 0; m < 2; ++m) {
      int rowA = (wr * 32 + m * 16 + rsel) * 64;
      af[m][0] = *(const bf16x8*)(As + rowA + slot0 * 8);
      af[m][1] = *(const bf16x8*)(As + rowA + slot1 * 8);
    }
    #pragma unroll
    for (int n = 0; n < 2; ++n) {
      int rowB = (wc * 32 + n * 16 + rsel) * 64;
      bfr[n][0] = *(const bf16x8*)(Bs + rowB + slot0 * 8);
      bfr[n][1] = *(const bf16x8*)(Bs + rowB + slot1 * 8);
    }
    #pragma unroll
    for (int m = 0; m < 2; ++m)
      #pragma unroll
      for (int n = 0; n < 2; ++n) {
        acc[m][n] = __builtin_amdgcn_mfma_f32_16x16x32_bf16(af[m][0], bfr[n][0], acc[m][n], 0, 0, 0);
        acc[m][n] = __builtin_amdgcn_mfma_f32_16x16x32_bf16(af[m][1], bfr[n][1], acc[m][n], 0, 0, 0);
      }
    __syncthreads();
  }

  float bvv[2];
  #pragma unroll
  for (int n = 0; n < 2; ++n) bvv[n] = b1[c0 + wc * 32 + n * 16 + rsel];
  #pragma unroll
  for (int m = 0; m < 2; ++m)
    #pragma unroll
    for (int i = 0; i < 4; ++i) {
      int g = g0 + wr * 32 + m * 16 + hi * 4 + i;
      float* xr = x1 + (size_t)g * D;
      #pragma unroll
      for (int n = 0; n < 2; ++n) {
        int c = c0 + wc * 32 + n * 16 + rsel;
        xr[c] = acc[m][n][i] + bvv[n];
      }
    }
}

// ---------------------------------------------------------------------------
// im2col: Xc[g][k*512+dp] = (l+k-6 >= 0) ? x[b][l+k-6][dp] : 0   (bf16)
__global__ void k_im2col(const float* __restrict__ x, unsigned short* __restrict__ Xc) {
  int g = blockIdx.x, tid = threadIdx.x;
  int b = g >> 5, l = g & 31;
  unsigned short* row = Xc + (size_t)g * KC;
  const float* xb = x + (size_t)b * L * D;
  int d = tid * 2;
  #pragma unroll
  for (int k = 0; k < KSZ; ++k) {
    int lp = l + k - 6;
    unsigned int pk = 0;
    if (lp >= 0) {
      float2 v = *(const float2*)(xb + (size_t)lp * D + d);
      pk = (unsigned int)f2bf(v.x) | ((unsigned int)f2bf(v.y) << 16);
    }
    *(unsigned int*)(row + k * 512 + d) = pk;
  }
}

// ---------------------------------------------------------------------------
// conv weight reorder+convert: wb[c][k*512+dp] = bf16(w[c][dp*7+k])
__global__ void k_cvt_wconv(const float* __restrict__ w, unsigned short* __restrict__ wb) {
  __shared__ float row[KC];  // 14 KiB
  int c = blockIdx.x, tid = threadIdx.x;
  const float* wr = w + (size_t)c * KC;
  for (int i = tid; i < KC; i += 256) row[i] = wr[i];
  __syncthreads();
  unsigned short* ob = wb + (size_t)c * KC;
  int dp = tid * 2;
  #pragma unroll
  for (int k = 0; k < KSZ; ++k) {
    unsigned int pk = (unsigned int)f2bf(row[dp * 7 + k]) |
                      ((unsigned int)f2bf(row[(dp + 1) * 7 + k]) << 16);
    *(unsigned int*)(ob + k * 512 + dp) = pk;
  }
}

// ---------------------------------------------------------------------------
// Fused Conv GEMM + GLU + residual, 3-buffer counted-vmcnt pipeline.
template <int OUT_BF16>
__global__ __launch_bounds__(256) void k_conv_glu(
    const unsigned short* __restrict__ Xc, const unsigned short* __restrict__ wb,
    const float* __restrict__ bias, const float* __restrict__ xres,
    float* __restrict__ outf, unsigned short* __restrict__ outh) {
  __shared__ __align__(16) unsigned char csmem[49152];  // 3x(A 8KB) | 3x(B 8KB)
  int c0 = blockIdx.x * 32, g0 = blockIdx.y * 64;
  int tid = threadIdx.x, lane = tid & 63, wave = tid >> 6;
  int wr = wave >> 1, wc = wave & 1;
  int rsel = lane & 15, hi = lane >> 4;

  f32x4 acc[2][2];
  #pragma unroll
  for (int m = 0; m < 2; ++m)
    #pragma unroll
    for (int n = 0; n < 2; ++n) acc[m][n] = (f32x4){0.f, 0.f, 0.f, 0.f};

  int r1 = tid >> 3, s1 = tid & 7;
  int sw = (s1 ^ (r1 & 7)) * 8;              // swizzled global k-segment
  const unsigned short* gA1 = Xc + (size_t)(g0 + r1) * KC + sw;
  const unsigned short* gA2 = Xc + (size_t)(g0 + r1 + 32) * KC + sw;
  const unsigned short* gB1 = wb + (size_t)(c0 + r1) * KC + sw;            // gate
  const unsigned short* gB2 = wb + (size_t)(512 + c0 + r1) * KC + sw;      // sigmoid

  int slot0 = hi ^ (rsel & 7);
  int slot1 = (4 + hi) ^ (rsel & 7);
  int wofs = wave * 512;

#define C_STAGE(bi)                                                        \
  do {                                                                     \
    unsigned short* aB = (unsigned short*)(csmem + (bi) * 8192);           \
    unsigned short* bB = (unsigned short*)(csmem + 24576 + (bi) * 8192);   \
    gload_lds16(gA1, aB + wofs);                                           \
    gload_lds16(gA2, aB + 2048 + wofs);                                    \
    gload_lds16(gB1, bB + wofs);                                           \
    gload_lds16(gB2, bB + 2048 + wofs);                                    \
    gA1 += 64; gA2 += 64; gB1 += 64; gB2 += 64;                            \
  } while (0)

  C_STAGE(0);
  C_STAGE(1);

  int sidx = 2, cidx = 0;
  for (int kt = 0; kt < KC / 64; ++kt) {
    if (kt < KC / 64 - 2) C_STAGE(sidx);
    __builtin_amdgcn_sched_barrier(0);
    if (kt < KC / 64 - 2)       asm volatile("s_waitcnt vmcnt(8)" ::: "memory");
    else if (kt == KC / 64 - 2) asm volatile("s_waitcnt vmcnt(4)" ::: "memory");
    else                        asm volatile("s_waitcnt vmcnt(0)" ::: "memory");
    __builtin_amdgcn_sched_barrier(0);
    __builtin_amdgcn_s_barrier();
    __builtin_amdgcn_sched_barrier(0);

    const unsigned short* Ac = (const unsigned short*)(csmem + cidx * 8192);
    const unsigned short* Bc = (const unsigned short*)(csmem + 24576 + cidx * 8192);
    bf16x8 af[2][2], bfr[2][2];
    #pragma unroll
    for (int m = 0; m < 2; ++m) {
      int rowA = (wr * 32 + m * 16 + rsel) * 64;
      af[m][0] = *(const bf16x8*)(Ac + rowA + slot0 * 8);
      af[m][1] = *(const bf16x8*)(Ac + rowA + slot1 * 8);
    }
    #pragma unroll
    for (int n = 0; n < 2; ++n) {
      int rowB = (wc * 32 + n * 16 + rsel) * 64;
      bfr[n][0] = *(const bf16x8*)(Bc + rowB + slot0 * 8);
      bfr[n][1] = *(const bf16x8*)(Bc + rowB + slot1 * 8);
    }
    #pragma unroll
    for (int m = 0; m < 2; ++m)
      #pragma unroll
      for (int n = 0; n < 2; ++n) {
        acc[m][n] = __builtin_amdgcn_mfma_f32_16x16x32_bf16(af[m][0], bfr[n][0], acc[m][n], 0, 0, 0);
        acc[m][n] = __builtin_amdgcn_mfma_f32_16x16x32_bf16(af[m][1], bfr[n][1], acc[m][n], 0, 0, 0);
      }
    __builtin_amdgcn_sched_barrier(0);
    __builtin_amdgcn_s_barrier();
    sidx = cidx;
    cidx = (cidx + 1 == 3) ? 0 : cidx + 1;
  }
#undef C_STAGE

  // Epilogue: GLU + residual. LDS pipeline dead — reuse as sb[64][33] fp32.
  float* sb = (float*)csmem;
  float bvv[2];
  #pragma unroll
  for (int n = 0; n < 2; ++n)
    bvv[n] = wc ? bias[512 + c0 + n * 16 + rsel] : bias[c0 + n * 16 + rsel];
  if (wc) {
    #pragma unroll
    for (int m = 0; m < 2; ++m)
      #pragma unroll
      for (int i = 0; i < 4; ++i) {
        int lr = wr * 32 + m * 16 + hi * 4 + i;
        #pragma unroll
        for (int n = 0; n < 2; ++n)
          sb[lr * 33 + n * 16 + rsel] = acc[m][n][i] + bvv[n];
      }
  }
  __syncthreads();
  if (!wc) {
    #pragma unroll
    for (int m = 0; m < 2; ++m)
      #pragma unroll
      for (int i = 0; i < 4; ++i) {
        int lr = wr * 32 + m * 16 + hi * 4 + i;
        int g = g0 + lr;
        const float* xr = xres + (size_t)g * 512 + c0;
        #pragma unroll
        for (int n = 0; n < 2; ++n) {
          int d = n * 16 + rsel;
          float ya = acc[m][n][i] + bvv[n];
          float yb = sb[lr * 33 + d];
          float val = ya / (1.f + expf(-yb)) + xr[d];
          if (OUT_BF16) outh[(size_t)g * 512 + c0 + d] = f2bf(val);
          else          outf[(size_t)g * 512 + c0 + d] = val;
        }
      }
  }
}

// ---------------------------------------------------------------------------
// cbase[b,v] = b2[v] + ctx[b,:1024] . W2[v,:1024]  as bf16 MFMA.
// Fused: also produces W2d[v][c] = bf16(W2[v][1024+c]) (replaces k_cvt_w2d).
__global__ __launch_bounds__(256) void k_cbase_mfma(
    const unsigned short* __restrict__ ctxb,  // [64][1024] bf16
    const float* __restrict__ W2,             // [30000][1536] fp32
    const float* __restrict__ b2, float* __restrict__ cbase,
    unsigned short* __restrict__ W2d) {
  __shared__ __align__(16) unsigned short As[64 * 64];    // 8 KB
  __shared__ __align__(16) unsigned short Bs[128 * 64];   // 16 KB
  int v0 = blockIdx.x * 128;
  int tid = threadIdx.x, lane = tid & 63, wave = tid >> 6;
  int rsel = lane & 15, hi = lane >> 4;
  int wc = wave;

  f32x4 acc[4][2];
  #pragma unroll
  for (int m = 0; m < 4; ++m)
    #pragma unroll
    for (int n = 0; n < 2; ++n) acc[m][n] = (f32x4){0.f, 0.f, 0.f, 0.f};

  int ra1 = tid >> 3, sa = tid & 7;
  int ra2 = ra1 + 32;
  const unsigned short* gA1 = ctxb + (size_t)ra1 * 1024 + (sa ^ (ra1 & 7)) * 8;
  const unsigned short* gA2 = ctxb + (size_t)ra2 * 1024 + (sa ^ (ra2 & 7)) * 8;
  unsigned short* aD1 = As + wave * 512;
  unsigned short* aD2 = As + 2048 + wave * 512;

  const float* gB[4];
  int bofs[4];
  #pragma unroll
  for (int p = 0; p < 4; ++p) {
    int row = p * 32 + (tid >> 3);
    int seg = tid & 7;
    int vr = v0 + row; if (vr > V - 1) vr = V - 1;
    gB[p] = W2 + (size_t)vr * (E_ENC + D) + seg * 8;
    bofs[p] = row * 64 + (seg ^ (row & 7)) * 8;
  }

  for (int kt = 0; kt < 16; ++kt) {
    gload_lds16(gA1, aD1);
    gload_lds16(gA2, aD2);
    gA1 += 64; gA2 += 64;
    #pragma unroll
    for (int p = 0; p < 4; ++p) {
      float4 f0 = *(const float4*)(gB[p]);
      float4 f1 = *(const float4*)(gB[p] + 4);
      gB[p] += 64;
      bf16x8 o;
      o[0] = (short)f2bf(f0.x); o[1] = (short)f2bf(f0.y);
      o[2] = (short)f2bf(f0.z); o[3] = (short)f2bf(f0.w);
      o[4] = (short)f2bf(f1.x); o[5] = (short)f2bf(f1.y);
      o[6] = (short)f2bf(f1.z); o[7] = (short)f2bf(f1.w);
      *(bf16x8*)(Bs + bofs[p]) = o;
    }
    __syncthreads();

    bf16x8 af[4][2], bfr[2][2];
    #pragma unroll
    for (int m = 0; m < 4; ++m) {
      int rowA = (m * 16 + rsel) * 64;
      #pragma unroll
      for (int kk = 0; kk < 2; ++kk)
        af[m][kk] = *(const bf16x8*)(As + rowA + ((kk * 4 + hi) ^ (rsel & 7)) * 8);
    }
    #pragma unroll
    for (int n = 0; n < 2; ++n) {
      int rowB = (wc * 32 + n * 16 + rsel) * 64;
      #pragma unroll
      for (int kk = 0; kk < 2; ++kk)
        bfr[n][kk] = *(const bf16x8*)(Bs + rowB + ((kk * 4 + hi) ^ (rsel & 7)) * 8);
    }
    #pragma unroll
    for (int kk = 0; kk < 2; ++kk)
      #pragma unroll
      for (int m = 0; m < 4; ++m)
        #pragma unroll
        for (int n = 0; n < 2; ++n)
          acc[m][n] = __builtin_amdgcn_mfma_f32_16x16x32_bf16(af[m][kk], bfr[n][kk], acc[m][n], 0, 0, 0);
    __syncthreads();
  }

  #pragma unroll
  for (int n = 0; n < 2; ++n) {
    int v = v0 + wc * 32 + n * 16 + rsel;
    if (v >= V) continue;
    float bias = b2[v];
    #pragma unroll
    for (int m = 0; m < 4; ++m)
      #pragma unroll
      for (int i = 0; i < 4; ++i) {
        int b = m * 16 + hi * 4 + i;
        cbase[(size_t)b * V + v] = acc[m][n][i] + bias;
      }
  }

  // Fused W2 decode-half conversion for rows v0..v0+127:
  // 128 rows x 128 float4/row = 16384 chunks; 256 threads x 64 iters, coalesced.
  for (int i = 0; i < 64; ++i) {
    int j = i * 256 + tid;
    int row = j >> 7, col = (j & 127) << 2;
    int vv = v0 + row;
    if (vv < V) {
      float4 f = *(const float4*)(W2 + (size_t)vv * (E_ENC + D) + E_ENC + col);
      ushort4 o;
      o.x = f2bf(f.x); o.y = f2bf(f.y); o.z = f2bf(f.z); o.w = f2bf(f.w);
      *(ushort4*)(W2d + (size_t)vv * D + col) = o;
    }
  }
}

// ---------------------------------------------------------------------------
// logits[b,s,v] = cbase[b,v] + x3[b,s,:] . W2d[v,:]
// 512 threads, tile 256g x 128v (8 waves of 64x64), BK=32, 4-slot XOR
// swizzle, XCD-bijective remap (1880 = 8*235, g fastest), 2-buffer
// counted-vmcnt(3) pipeline (48 KB), LDS-transposed float4 epilogue.
__global__ __launch_bounds__(512) void k_logits_mfma(
    const unsigned short* __restrict__ Ab,   // x3 bf16 [2048][512]
    const unsigned short* __restrict__ Bb,   // W2d bf16 [30000][512]
    const float* __restrict__ cbase, float* __restrict__ out) {
  __shared__ __align__(16) unsigned char smem[49152];  // A 2x16KB | B 2x8KB
  int flat = blockIdx.x;                  // 1880 = 8 * 235
  int ord = (flat & 7) * 235 + (flat >> 3);
  int v0 = (ord >> 3) * 128;              // 235 v-tiles
  int g0 = (ord & 7) * 256;               // 8 g-tiles (g fastest within XCD)
  int tid = threadIdx.x, lane = tid & 63, wave = tid >> 6;   // 0..7
  int wg = wave >> 1, wv = wave & 1;      // wave -> 64g x 64v quadrant
  int rsel = lane & 15, hi = lane >> 4;

  f32x4 acc[4][4];
  #pragma unroll
  for (int m = 0; m < 4; ++m)
    #pragma unroll
    for (int n = 0; n < 4; ++n) acc[m][n] = (f32x4){0.f, 0.f, 0.f, 0.f};

  // staging: chunk c: row c>>2, phys slot c&3; global segment = slot ^ ((row>>1)&3)
  int r1 = tid >> 2, s1 = tid & 3;
  int seg = (s1 ^ ((r1 >> 1) & 3)) * 8;
  const unsigned short* gA1 = Ab + (size_t)(g0 + r1) * 512 + seg;
  const unsigned short* gA2 = Ab + (size_t)(g0 + r1 + 128) * 512 + seg;
  int vr = v0 + r1; if (vr > V - 1) vr = V - 1;
  const unsigned short* gB1 = Bb + (size_t)vr * 512 + seg;

  int wofs = wave * 512;   // shorts; 64 lanes x 16B = 1KB per wave

#define L_STAGE(bi)                                                        \
  do {                                                                     \
    unsigned short* aB = (unsigned short*)(smem + (bi) * 16384);           \
    unsigned short* bB = (unsigned short*)(smem + 32768 + (bi) * 8192);    \
    gload_lds16(gA1, aB + wofs);                                           \
    gload_lds16(gA2, aB + 4096 + wofs);                                    \
    gload_lds16(gB1, bB + wofs);                                           \
    gA1 += 32; gA2 += 32; gB1 += 32;                                       \
  } while (0)

  L_STAGE(0);
  L_STAGE(1);

  int sl = (rsel >> 1) & 3;   // read-side swizzle term
  for (int kt = 0; kt < 16; ++kt) {
    __builtin_amdgcn_sched_barrier(0);
    if (kt < 15) asm volatile("s_waitcnt vmcnt(3)" ::: "memory");
    else         asm volatile("s_waitcnt vmcnt(0)" ::: "memory");
    __builtin_amdgcn_sched_barrier(0);
    __builtin_amdgcn_s_barrier();       // stage kt complete for all waves
    __builtin_amdgcn_sched_barrier(0);

    const unsigned short* Ac = (const unsigned short*)(smem + (kt & 1) * 16384);
    const unsigned short* Bc = (const unsigned short*)(smem + 32768 + (kt & 1) * 8192);
    bf16x8 af[4], bfr[4];
    #pragma unroll
    for (int m = 0; m < 4; ++m)
      af[m] = *(const bf16x8*)(Ac + (wg * 64 + m * 16 + rsel) * 32 + ((hi ^ sl) * 8));
    #pragma unroll
    for (int n = 0; n < 4; ++n)
      bfr[n] = *(const bf16x8*)(Bc + (wv * 64 + n * 16 + rsel) * 32 + ((hi ^ sl) * 8));
    #pragma unroll
    for (int m = 0; m < 4; ++m)
      #pragma unroll
      for (int n = 0; n < 4; ++n)
        acc[m][n] = __builtin_amdgcn_mfma_f32_16x16x32_bf16(af[m], bfr[n], acc[m][n], 0, 0, 0);

    __builtin_amdgcn_sched_barrier(0);
    __builtin_amdgcn_s_barrier();       // buffer kt free for restage
    __builtin_amdgcn_sched_barrier(0);
    if (kt + 2 < 16) L_STAGE(kt & 1);   // stage t+2 into the buffer just freed
  }
#undef L_STAGE

  // Epilogue: LDS transpose -> float4 coalesced stores, 4 passes (g quarters).
  __syncthreads();
  float* ebuf = (float*)smem;   // [64][132] = 33792 B <= 49152
  #pragma unroll
  for (int p = 0; p < 4; ++p) {
    if (p) __syncthreads();
    if (wg == p) {
      #pragma unroll
      for (int m = 0; m < 4; ++m)
        #pragma unroll
        for (int i = 0; i < 4; ++i) {
          int lr = m * 16 + hi * 4 + i;
          #pragma unroll
          for (int n = 0; n < 4; ++n)
            ebuf[lr * 132 + wv * 64 + n * 16 + rsel] = acc[m][n][i];
        }
    }
    __syncthreads();
    #pragma unroll
    for (int j = 0; j < 4; ++j) {
      int f = tid + j * 512;                 // 0..2047: 64 rows x 32 float4
      int lr = f >> 5, c4 = (f & 31) * 4;
      int g = g0 + p * 64 + lr;
      int b = g >> 5, lt = g & 31;
      int v = v0 + c4;
      if (lt < S && v < V) {
        float4 val = *(const float4*)(ebuf + lr * 132 + c4);
        float4 cb4 = *(const float4*)(cbase + (size_t)b * V + v);
        float4 o;
        o.x = val.x + cb4.x; o.y = val.y + cb4.y;
        o.z = val.z + cb4.z; o.w = val.w + cb4.w;
        *(float4*)(out + ((size_t)b * S + lt) * V + v) = o;
      }
    }
  }
}

// ---------------------------------------------------------------------------
extern "C" void kernel_launch(void* const* d_in, const int* in_sizes, int n_in,
                              void* d_out, int out_size, void* d_ws, size_t ws_size,
                              hipStream_t stream) {
  const float* features = (const float*)d_in[0];
  const int*   captions = (const int*)d_in[1];
  const float* embed_W  = (const float*)d_in[3];
  const float* W1   = (const float*)d_in[4];
  const float* b1   = (const float*)d_in[5];
  const float* cw1  = (const float*)d_in[6];
  const float* cb1  = (const float*)d_in[7];
  const float* cw2  = (const float*)d_in[8];
  const float* cb2  = (const float*)d_in[9];
  const float* Wenc = (const float*)d_in[10];
  const float* benc = (const float*)d_in[11];
  const float* Wp   = (const float*)d_in[14];
  const float* W2   = (const float*)d_in[16];
  const float* b2   = (const float*)d_in[17];
  float* out = (float*)d_out;

  float* ws = (float*)d_ws;
  float* wv       = ws;                 // 1024
  float* c0       = ws + 1024;          // 16
  unsigned short* enc_meanb = (unsigned short*)(ws + 1040);  // 65536 bf16
  unsigned short* ctxb = (unsigned short*)(ws + 66576);      // 65536 bf16
  float* xA       = ws + 164880;        // 1048576 (x1; x3b overlays later)
  float* xB       = ws + 1213456;       // 1048576 (x2)
  float* cbase    = ws + 2262032;       // 1920000
  unsigned short* x3b  = (unsigned short*)xA;             // 1048576 bf16 (xA dead)
  unsigned short* Xc   = (unsigned short*)(ws + 4359184); // 7340032 bf16
  unsigned short* wbuf = (unsigned short*)(ws + 8029200); // 3670016 bf16
  unsigned short* W2d  = (unsigned short*)(ws + 9864208); // 15360000 bf16
  unsigned short* Xe  = Xc;                  // 1048576 bf16 (pre-im2col)
  unsigned short* w1b = Xc + 1048576;        // 786432 bf16 (full W1)
  // end: 17,544,208 floats = 70.2 MB (unchanged)

  hipLaunchKernelGGL(k_wv,       dim3(16),      dim3(256), 0, stream, Wenc, Wp, benc, wv, c0);
  hipLaunchKernelGGL(k_mean_ctx, dim3(B),       dim3(256), 0, stream, features, wv, c0, enc_meanb, ctxb);

  // x1 = b1 + [enc_mean||emb] @ W1ᵀ  (fused MFMA, K=1536)
  hipLaunchKernelGGL(k_gather_emb, dim3(2048),  dim3(256), 0, stream, embed_W, captions, Xe);
  hipLaunchKernelGGL(k_cvt_w1,     dim3(512),   dim3(256), 0, stream, W1, w1b);
  hipLaunchKernelGGL(k_x1f_mfma,   dim3(8, 32), dim3(256), 0, stream, enc_meanb, Xe, w1b, b1, xA);

  // conv layer 1 (GEMM+GLU fused; writes gated+res fp32 into xB)
  hipLaunchKernelGGL(k_cvt_wconv,   dim3(1024),   dim3(256), 0, stream, cw1, wbuf);
  hipLaunchKernelGGL(k_im2col,      dim3(2048),   dim3(256), 0, stream, xA, Xc);
  hipLaunchKernelGGL(k_conv_glu<0>, dim3(16, 32), dim3(256), 0, stream, Xc, wbuf, cb1, xA, xB, (unsigned short*)nullptr);

  // conv layer 2 (writes bf16 x3 directly)
  hipLaunchKernelGGL(k_cvt_wconv,   dim3(1024),   dim3(256), 0, stream, cw2, wbuf);
  hipLaunchKernelGGL(k_im2col,      dim3(2048),   dim3(256), 0, stream, xB, Xc);
  hipLaunchKernelGGL(k_conv_glu<1>, dim3(16, 32), dim3(256), 0, stream, Xc, wbuf, cb2, xB, (float*)nullptr, x3b);

  // cbase + fused W2 decode-half conversion (replaces k_cvt_w2d)
  hipLaunchKernelGGL(k_cbase_mfma, dim3(235),   dim3(256), 0, stream, ctxb, W2, b2, cbase, W2d);
  hipLaunchKernelGGL(k_logits_mfma, dim3(1880), dim3(512), 0, stream, x3b, W2d, cbase, out);
}

// Round 18
// 354.940 us; speedup vs baseline: 1.0081x; 1.0081x over previous
//
#include <hip/hip_runtime.h>
#include <hip/hip_bf16.h>
#include <math.h>

// Sizes (fixed by the problem)
#define B 64
#define T 64
#define E_ENC 1024
#define EMB 512
#define D 512
#define L 32
#define S 31
#define A 512
#define V 30000
#define KSZ 7
#define KC (D * KSZ)   // 3584 = conv GEMM K

typedef __attribute__((ext_vector_type(8))) short bf16x8;
typedef __attribute__((ext_vector_type(4))) float f32x4;

__device__ __forceinline__ unsigned short f2bf(float f) {
  union { float f; unsigned int u; } x; x.f = f;
  unsigned int r = (x.u + 0x7fffu + ((x.u >> 16) & 1u)) >> 16;
  return (unsigned short)r;
}

__device__ __forceinline__ void gload_lds16(const void* g, void* l) {
  __builtin_amdgcn_global_load_lds(
      (const __attribute__((address_space(1))) unsigned int*)g,
      (__attribute__((address_space(3))) unsigned int*)l, 16, 0, 0);
}

// ---------------------------------------------------------------------------
// wv[e] = sum_a Wp[a]*Wenc[a,e];  c0 = sum_a benc[a]*Wp[a]
__global__ void k_wv(const float* __restrict__ Wenc, const float* __restrict__ Wp,
                     const float* __restrict__ benc, float* __restrict__ wv,
                     float* __restrict__ c0) {
  __shared__ float sp[4][64];
  __shared__ float red[256];
  int el = threadIdx.x & 63, part = threadIdx.x >> 6;
  int e = blockIdx.x * 64 + el;
  float s = 0.f;
  for (int a = part * 128; a < part * 128 + 128; ++a)
    s += Wp[a] * Wenc[(size_t)a * E_ENC + e];
  sp[part][el] = s;
  __syncthreads();
  if (part == 0) wv[e] = sp[0][el] + sp[1][el] + sp[2][el] + sp[3][el];
  if (blockIdx.x == 0) {
    int t = threadIdx.x;
    float v = Wp[t] * benc[t] + Wp[t + 256] * benc[t + 256];
    red[t] = v;
    __syncthreads();
    for (int off = 128; off > 0; off >>= 1) {
      if (t < off) red[t] += red[t + off];
      __syncthreads();
    }
    if (t == 0) c0[0] = red[0];
  }
}

// ---------------------------------------------------------------------------
// Per-b: enc_mean (bf16), fscore -> softmax over t -> ctx (bf16)
__global__ void k_mean_ctx(const float* __restrict__ features, const float* __restrict__ wv,
                           const float* __restrict__ c0, unsigned short* __restrict__ enc_meanb,
                           unsigned short* __restrict__ ctxb) {
  int b = blockIdx.x, tid = threadIdx.x;
  const float* fb = features + (size_t)b * T * E_ENC;
  __shared__ float s_attw[T];

  float m0 = 0, m1 = 0, m2 = 0, m3 = 0;
  for (int t = 0; t < T; ++t) {
    const float* r = fb + t * E_ENC;
    m0 += r[tid]; m1 += r[tid + 256]; m2 += r[tid + 512]; m3 += r[tid + 768];
  }
  size_t eb = (size_t)b * E_ENC;
  enc_meanb[eb + tid]       = f2bf(m0 * (1.f / 64.f));
  enc_meanb[eb + tid + 256] = f2bf(m1 * (1.f / 64.f));
  enc_meanb[eb + tid + 512] = f2bf(m2 * (1.f / 64.f));
  enc_meanb[eb + tid + 768] = f2bf(m3 * (1.f / 64.f));

  {
    int t = tid >> 2, part = tid & 3;
    const float* r = fb + t * E_ENC + part * 256;
    const float* wp = wv + part * 256;
    float s = 0.f;
    for (int e = 0; e < 256; e += 4) {
      float4 f4 = *(const float4*)(r + e);
      float4 w4 = *(const float4*)(wp + e);
      s += f4.x * w4.x + f4.y * w4.y + f4.z * w4.z + f4.w * w4.w;
    }
    s += __shfl_xor(s, 1);
    s += __shfl_xor(s, 2);
    if (part == 0) s_attw[t] = s + c0[0];
  }
  __syncthreads();
  if (tid < 64) {
    float v = s_attw[tid];
    float mx = v;
    #pragma unroll
    for (int off = 32; off > 0; off >>= 1) mx = fmaxf(mx, __shfl_xor(mx, off));
    float e = expf(v - mx);
    float sm = e;
    #pragma unroll
    for (int off = 32; off > 0; off >>= 1) sm += __shfl_xor(sm, off);
    s_attw[tid] = e / sm;
  }
  __syncthreads();
  float ca = 0, cb = 0, cc = 0, cd = 0;
  for (int t = 0; t < T; ++t) {
    float w = s_attw[t];
    const float* r = fb + t * E_ENC;
    ca += w * r[tid]; cb += w * r[tid + 256]; cc += w * r[tid + 512]; cd += w * r[tid + 768];
  }
  ctxb[eb + tid]       = f2bf(ca);
  ctxb[eb + tid + 256] = f2bf(cb);
  ctxb[eb + tid + 512] = f2bf(cc);
  ctxb[eb + tid + 768] = f2bf(cd);
}

// ---------------------------------------------------------------------------
// Gather embedding rows per caption token -> bf16 Xe[2048][512]
__global__ void k_gather_emb(const float* __restrict__ embed_W,
                             const int* __restrict__ captions,
                             unsigned short* __restrict__ Xe) {
  int g = blockIdx.x, tid = threadIdx.x;
  int cap = captions[g];
  const float* src = embed_W + (size_t)cap * EMB;
  float2 v = *(const float2*)(src + tid * 2);
  unsigned int pk = (unsigned int)f2bf(v.x) | ((unsigned int)f2bf(v.y) << 16);
  *(unsigned int*)(Xe + (size_t)g * EMB + tid * 2) = pk;
}

// Full W1 conversion: w1b[d][k] = bf16(W1[d][k])
__global__ void k_cvt_w1(const float* __restrict__ W1, unsigned short* __restrict__ w1b) {
  int d = blockIdx.x, tid = threadIdx.x;
  #pragma unroll
  for (int i = 0; i < 3; ++i) {
    int c = tid * 2 + i * 512;
    float2 v = *(const float2*)(W1 + (size_t)d * (E_ENC + EMB) + c);
    unsigned int pk = (unsigned int)f2bf(v.x) | ((unsigned int)f2bf(v.y) << 16);
    *(unsigned int*)(w1b + (size_t)d * (E_ENC + EMB) + c) = pk;
  }
}

// ---------------------------------------------------------------------------
// Fused x1 GEMM: x1[g][d] = b1[d] + [enc_mean(b)||emb(g)] . w1b[d,:]
__global__ __launch_bounds__(256) void k_x1f_mfma(
    const unsigned short* __restrict__ enc_meanb,  // [64][1024] bf16
    const unsigned short* __restrict__ Xe,         // [2048][512] bf16
    const unsigned short* __restrict__ w1b,        // [512][1536] bf16
    const float* __restrict__ b1, float* __restrict__ x1) {
  __shared__ __align__(16) unsigned short As[64 * 64];  // 8 KB
  __shared__ __align__(16) unsigned short Bs[64 * 64];  // 8 KB
  int c0 = blockIdx.x * 64, g0 = blockIdx.y * 64;
  int tid = threadIdx.x, lane = tid & 63, wave = tid >> 6;
  int wr = wave >> 1, wc = wave & 1;
  int rsel = lane & 15, hi = lane >> 4;

  f32x4 acc[2][2];
  #pragma unroll
  for (int m = 0; m < 2; ++m)
    #pragma unroll
    for (int n = 0; n < 2; ++n) acc[m][n] = (f32x4){0.f, 0.f, 0.f, 0.f};

  int r1 = tid >> 3, s1 = tid & 7;
  int sw = (s1 ^ (r1 & 7)) * 8;
  const unsigned short* emA1 = enc_meanb + (size_t)(g0 >> 5) * 1024 + sw;
  const unsigned short* emA2 = enc_meanb + (size_t)((g0 >> 5) + 1) * 1024 + sw;
  const unsigned short* xeA1 = Xe + (size_t)(g0 + r1) * 512 + sw;
  const unsigned short* xeA2 = Xe + (size_t)(g0 + r1 + 32) * 512 + sw;
  const unsigned short* gB1 = w1b + (size_t)(c0 + r1) * (E_ENC + EMB) + sw;
  const unsigned short* gB2 = w1b + (size_t)(c0 + r1 + 32) * (E_ENC + EMB) + sw;
  unsigned short* aD1 = As + wave * 512;
  unsigned short* aD2 = As + 2048 + wave * 512;
  unsigned short* bD1 = Bs + wave * 512;
  unsigned short* bD2 = Bs + 2048 + wave * 512;

  int slot0 = hi ^ (rsel & 7);
  int slot1 = (4 + hi) ^ (rsel & 7);

  for (int kt = 0; kt < 24; ++kt) {
    const unsigned short *pA1, *pA2;
    if (kt < 16) { pA1 = emA1 + kt * 64; pA2 = emA2 + kt * 64; }
    else         { pA1 = xeA1 + (kt - 16) * 64; pA2 = xeA2 + (kt - 16) * 64; }
    gload_lds16(pA1, aD1);
    gload_lds16(pA2, aD2);
    gload_lds16(gB1, bD1);
    gload_lds16(gB2, bD2);
    gB1 += 64; gB2 += 64;
    __syncthreads();

    bf16x8 af[2][2], bfr[2][2];
    #pragma unroll
    for (int m = 0; m < 2; ++m) {
      int rowA = (wr * 32 + m * 16 + rsel) * 64;
      af[m][0] = *(const bf16x8*)(As + rowA + slot0 * 8);
      af[m][1] = *(const bf16x8*)(As + rowA + slot1 * 8);
    }
    #pragma unroll
    for (int n = 0; n < 2; ++n) {
      int rowB = (wc * 32 + n * 16 + rsel) * 64;
      bfr[n][0] = *(const bf16x8*)(Bs + rowB + slot0 * 8);
      bfr[n][1] = *(const bf16x8*)(Bs + rowB + slot1 * 8);
    }
    #pragma unroll
    for (int m = 0; m < 2; ++m)
      #pragma unroll
      for (int n = 0; n < 2; ++n) {
        acc[m][n] = __builtin_amdgcn_mfma_f32_16x16x32_bf16(af[m][0], bfr[n][0], acc[m][n], 0, 0, 0);
        acc[m][n] = __builtin_amdgcn_mfma_f32_16x16x32_bf16(af[m][1], bfr[n][1], acc[m][n], 0, 0, 0);
      }
    __syncthreads();
  }

  float bvv[2];
  #pragma unroll
  for (int n = 0; n < 2; ++n) bvv[n] = b1[c0 + wc * 32 + n * 16 + rsel];
  #pragma unroll
  for (int m = 0; m < 2; ++m)
    #pragma unroll
    for (int i = 0; i < 4; ++i) {
      int g = g0 + wr * 32 + m * 16 + hi * 4 + i;
      float* xr = x1 + (size_t)g * D;
      #pragma unroll
      for (int n = 0; n < 2; ++n) {
        int c = c0 + wc * 32 + n * 16 + rsel;
        xr[c] = acc[m][n][i] + bvv[n];
      }
    }
}

// ---------------------------------------------------------------------------
// im2col: Xc[g][k*512+dp] = (l+k-6 >= 0) ? x[b][l+k-6][dp] : 0   (bf16)
__global__ void k_im2col(const float* __restrict__ x, unsigned short* __restrict__ Xc) {
  int g = blockIdx.x, tid = threadIdx.x;
  int b = g >> 5, l = g & 31;
  unsigned short* row = Xc + (size_t)g * KC;
  const float* xb = x + (size_t)b * L * D;
  int d = tid * 2;
  #pragma unroll
  for (int k = 0; k < KSZ; ++k) {
    int lp = l + k - 6;
    unsigned int pk = 0;
    if (lp >= 0) {
      float2 v = *(const float2*)(xb + (size_t)lp * D + d);
      pk = (unsigned int)f2bf(v.x) | ((unsigned int)f2bf(v.y) << 16);
    }
    *(unsigned int*)(row + k * 512 + d) = pk;
  }
}

// ---------------------------------------------------------------------------
// conv weight reorder+convert: wb[c][k*512+dp] = bf16(w[c][dp*7+k])
__global__ void k_cvt_wconv(const float* __restrict__ w, unsigned short* __restrict__ wb) {
  __shared__ float row[KC];  // 14 KiB
  int c = blockIdx.x, tid = threadIdx.x;
  const float* wr = w + (size_t)c * KC;
  for (int i = tid; i < KC; i += 256) row[i] = wr[i];
  __syncthreads();
  unsigned short* ob = wb + (size_t)c * KC;
  int dp = tid * 2;
  #pragma unroll
  for (int k = 0; k < KSZ; ++k) {
    unsigned int pk = (unsigned int)f2bf(row[dp * 7 + k]) |
                      ((unsigned int)f2bf(row[(dp + 1) * 7 + k]) << 16);
    *(unsigned int*)(ob + k * 512 + dp) = pk;
  }
}

// ---------------------------------------------------------------------------
// Fused Conv GEMM + GLU + residual, 3-buffer counted-vmcnt pipeline.
template <int OUT_BF16>
__global__ __launch_bounds__(256) void k_conv_glu(
    const unsigned short* __restrict__ Xc, const unsigned short* __restrict__ wb,
    const float* __restrict__ bias, const float* __restrict__ xres,
    float* __restrict__ outf, unsigned short* __restrict__ outh) {
  __shared__ __align__(16) unsigned char csmem[49152];  // 3x(A 8KB) | 3x(B 8KB)
  int c0 = blockIdx.x * 32, g0 = blockIdx.y * 64;
  int tid = threadIdx.x, lane = tid & 63, wave = tid >> 6;
  int wr = wave >> 1, wc = wave & 1;
  int rsel = lane & 15, hi = lane >> 4;

  f32x4 acc[2][2];
  #pragma unroll
  for (int m = 0; m < 2; ++m)
    #pragma unroll
    for (int n = 0; n < 2; ++n) acc[m][n] = (f32x4){0.f, 0.f, 0.f, 0.f};

  int r1 = tid >> 3, s1 = tid & 7;
  int sw = (s1 ^ (r1 & 7)) * 8;              // swizzled global k-segment
  const unsigned short* gA1 = Xc + (size_t)(g0 + r1) * KC + sw;
  const unsigned short* gA2 = Xc + (size_t)(g0 + r1 + 32) * KC + sw;
  const unsigned short* gB1 = wb + (size_t)(c0 + r1) * KC + sw;            // gate
  const unsigned short* gB2 = wb + (size_t)(512 + c0 + r1) * KC + sw;      // sigmoid

  int slot0 = hi ^ (rsel & 7);
  int slot1 = (4 + hi) ^ (rsel & 7);
  int wofs = wave * 512;

#define C_STAGE(bi)                                                        \
  do {                                                                     \
    unsigned short* aB = (unsigned short*)(csmem + (bi) * 8192);           \
    unsigned short* bB = (unsigned short*)(csmem + 24576 + (bi) * 8192);   \
    gload_lds16(gA1, aB + wofs);                                           \
    gload_lds16(gA2, aB + 2048 + wofs);                                    \
    gload_lds16(gB1, bB + wofs);                                           \
    gload_lds16(gB2, bB + 2048 + wofs);                                    \
    gA1 += 64; gA2 += 64; gB1 += 64; gB2 += 64;                            \
  } while (0)

  C_STAGE(0);
  C_STAGE(1);

  int sidx = 2, cidx = 0;
  for (int kt = 0; kt < KC / 64; ++kt) {
    if (kt < KC / 64 - 2) C_STAGE(sidx);
    __builtin_amdgcn_sched_barrier(0);
    if (kt < KC / 64 - 2)       asm volatile("s_waitcnt vmcnt(8)" ::: "memory");
    else if (kt == KC / 64 - 2) asm volatile("s_waitcnt vmcnt(4)" ::: "memory");
    else                        asm volatile("s_waitcnt vmcnt(0)" ::: "memory");
    __builtin_amdgcn_sched_barrier(0);
    __builtin_amdgcn_s_barrier();
    __builtin_amdgcn_sched_barrier(0);

    const unsigned short* Ac = (const unsigned short*)(csmem + cidx * 8192);
    const unsigned short* Bc = (const unsigned short*)(csmem + 24576 + cidx * 8192);
    bf16x8 af[2][2], bfr[2][2];
    #pragma unroll
    for (int m = 0; m < 2; ++m) {
      int rowA = (wr * 32 + m * 16 + rsel) * 64;
      af[m][0] = *(const bf16x8*)(Ac + rowA + slot0 * 8);
      af[m][1] = *(const bf16x8*)(Ac + rowA + slot1 * 8);
    }
    #pragma unroll
    for (int n = 0; n < 2; ++n) {
      int rowB = (wc * 32 + n * 16 + rsel) * 64;
      bfr[n][0] = *(const bf16x8*)(Bc + rowB + slot0 * 8);
      bfr[n][1] = *(const bf16x8*)(Bc + rowB + slot1 * 8);
    }
    #pragma unroll
    for (int m = 0; m < 2; ++m)
      #pragma unroll
      for (int n = 0; n < 2; ++n) {
        acc[m][n] = __builtin_amdgcn_mfma_f32_16x16x32_bf16(af[m][0], bfr[n][0], acc[m][n], 0, 0, 0);
        acc[m][n] = __builtin_amdgcn_mfma_f32_16x16x32_bf16(af[m][1], bfr[n][1], acc[m][n], 0, 0, 0);
      }
    __builtin_amdgcn_sched_barrier(0);
    __builtin_amdgcn_s_barrier();
    sidx = cidx;
    cidx = (cidx + 1 == 3) ? 0 : cidx + 1;
  }
#undef C_STAGE

  // Epilogue: GLU + residual. LDS pipeline dead — reuse as sb[64][33] fp32.
  float* sb = (float*)csmem;
  float bvv[2];
  #pragma unroll
  for (int n = 0; n < 2; ++n)
    bvv[n] = wc ? bias[512 + c0 + n * 16 + rsel] : bias[c0 + n * 16 + rsel];
  if (wc) {
    #pragma unroll
    for (int m = 0; m < 2; ++m)
      #pragma unroll
      for (int i = 0; i < 4; ++i) {
        int lr = wr * 32 + m * 16 + hi * 4 + i;
        #pragma unroll
        for (int n = 0; n < 2; ++n)
          sb[lr * 33 + n * 16 + rsel] = acc[m][n][i] + bvv[n];
      }
  }
  __syncthreads();
  if (!wc) {
    #pragma unroll
    for (int m = 0; m < 2; ++m)
      #pragma unroll
      for (int i = 0; i < 4; ++i) {
        int lr = wr * 32 + m * 16 + hi * 4 + i;
        int g = g0 + lr;
        const float* xr = xres + (size_t)g * 512 + c0;
        #pragma unroll
        for (int n = 0; n < 2; ++n) {
          int d = n * 16 + rsel;
          float ya = acc[m][n][i] + bvv[n];
          float yb = sb[lr * 33 + d];
          float val = ya / (1.f + expf(-yb)) + xr[d];
          if (OUT_BF16) outh[(size_t)g * 512 + c0 + d] = f2bf(val);
          else          outf[(size_t)g * 512 + c0 + d] = val;
        }
      }
  }
}

// ---------------------------------------------------------------------------
// cbase[b,v] = b2[v] + ctx[b,:1024] . W2[v,:1024]  as bf16 MFMA.
__global__ __launch_bounds__(256) void k_cbase_mfma(
    const unsigned short* __restrict__ ctxb,  // [64][1024] bf16
    const float* __restrict__ W2,             // [30000][1536] fp32
    const float* __restrict__ b2, float* __restrict__ cbase) {
  __shared__ __align__(16) unsigned short As[64 * 64];    // 8 KB
  __shared__ __align__(16) unsigned short Bs[128 * 64];   // 16 KB
  int v0 = blockIdx.x * 128;
  int tid = threadIdx.x, lane = tid & 63, wave = tid >> 6;
  int rsel = lane & 15, hi = lane >> 4;
  int wc = wave;

  f32x4 acc[4][2];
  #pragma unroll
  for (int m = 0; m < 4; ++m)
    #pragma unroll
    for (int n = 0; n < 2; ++n) acc[m][n] = (f32x4){0.f, 0.f, 0.f, 0.f};

  int ra1 = tid >> 3, sa = tid & 7;
  int ra2 = ra1 + 32;
  const unsigned short* gA1 = ctxb + (size_t)ra1 * 1024 + (sa ^ (ra1 & 7)) * 8;
  const unsigned short* gA2 = ctxb + (size_t)ra2 * 1024 + (sa ^ (ra2 & 7)) * 8;
  unsigned short* aD1 = As + wave * 512;
  unsigned short* aD2 = As + 2048 + wave * 512;

  const float* gB[4];
  int bofs[4];
  #pragma unroll
  for (int p = 0; p < 4; ++p) {
    int row = p * 32 + (tid >> 3);
    int seg = tid & 7;
    int vr = v0 + row; if (vr > V - 1) vr = V - 1;
    gB[p] = W2 + (size_t)vr * (E_ENC + D) + seg * 8;
    bofs[p] = row * 64 + (seg ^ (row & 7)) * 8;
  }

  for (int kt = 0; kt < 16; ++kt) {
    gload_lds16(gA1, aD1);
    gload_lds16(gA2, aD2);
    gA1 += 64; gA2 += 64;
    #pragma unroll
    for (int p = 0; p < 4; ++p) {
      float4 f0 = *(const float4*)(gB[p]);
      float4 f1 = *(const float4*)(gB[p] + 4);
      gB[p] += 64;
      bf16x8 o;
      o[0] = (short)f2bf(f0.x); o[1] = (short)f2bf(f0.y);
      o[2] = (short)f2bf(f0.z); o[3] = (short)f2bf(f0.w);
      o[4] = (short)f2bf(f1.x); o[5] = (short)f2bf(f1.y);
      o[6] = (short)f2bf(f1.z); o[7] = (short)f2bf(f1.w);
      *(bf16x8*)(Bs + bofs[p]) = o;
    }
    __syncthreads();

    bf16x8 af[4][2], bfr[2][2];
    #pragma unroll
    for (int m = 0; m < 4; ++m) {
      int rowA = (m * 16 + rsel) * 64;
      #pragma unroll
      for (int kk = 0; kk < 2; ++kk)
        af[m][kk] = *(const bf16x8*)(As + rowA + ((kk * 4 + hi) ^ (rsel & 7)) * 8);
    }
    #pragma unroll
    for (int n = 0; n < 2; ++n) {
      int rowB = (wc * 32 + n * 16 + rsel) * 64;
      #pragma unroll
      for (int kk = 0; kk < 2; ++kk)
        bfr[n][kk] = *(const bf16x8*)(Bs + rowB + ((kk * 4 + hi) ^ (rsel & 7)) * 8);
    }
    #pragma unroll
    for (int kk = 0; kk < 2; ++kk)
      #pragma unroll
      for (int m = 0; m < 4; ++m)
        #pragma unroll
        for (int n = 0; n < 2; ++n)
          acc[m][n] = __builtin_amdgcn_mfma_f32_16x16x32_bf16(af[m][kk], bfr[n][kk], acc[m][n], 0, 0, 0);
    __syncthreads();
  }

  #pragma unroll
  for (int n = 0; n < 2; ++n) {
    int v = v0 + wc * 32 + n * 16 + rsel;
    if (v >= V) continue;
    float bias = b2[v];
    #pragma unroll
    for (int m = 0; m < 4; ++m)
      #pragma unroll
      for (int i = 0; i < 4; ++i) {
        int b = m * 16 + hi * 4 + i;
        cbase[(size_t)b * V + v] = acc[m][n][i] + bias;
      }
  }
}

// ---------------------------------------------------------------------------
// W2 decode-half conversion: y[v][c] = bf16(W2[v][1024+c])
__global__ void k_cvt_w2d(const float* __restrict__ W2, unsigned short* __restrict__ y) {
  int i = blockIdx.x * 256 + threadIdx.x;
  int row = i >> 7, c = (i & 127) << 2;
  float4 f = *(const float4*)(W2 + (size_t)row * (E_ENC + D) + E_ENC + c);
  ushort4 o;
  o.x = f2bf(f.x); o.y = f2bf(f.y); o.z = f2bf(f.z); o.w = f2bf(f.w);
  *(ushort4*)(y + (size_t)row * D + c) = o;
}

// ---------------------------------------------------------------------------
// logits[b,s,v] = cbase[b,v] + x3[b,s,:] . W2d[v,:]
// 512 threads, tile 256g x 128v (8 waves of 64x64), BK=32, 4-slot XOR
// swizzle, XCD-bijective remap (1880 = 8*235, g fastest), 2-buffer
// counted-vmcnt(3) pipeline (48 KB), LDS-transposed float4 epilogue.
__global__ __launch_bounds__(512) void k_logits_mfma(
    const unsigned short* __restrict__ Ab,   // x3 bf16 [2048][512]
    const unsigned short* __restrict__ Bb,   // W2d bf16 [30000][512]
    const float* __restrict__ cbase, float* __restrict__ out) {
  __shared__ __align__(16) unsigned char smem[49152];  // A 2x16KB | B 2x8KB
  int flat = blockIdx.x;                  // 1880 = 8 * 235
  int ord = (flat & 7) * 235 + (flat >> 3);
  int v0 = (ord >> 3) * 128;              // 235 v-tiles
  int g0 = (ord & 7) * 256;               // 8 g-tiles (g fastest within XCD)
  int tid = threadIdx.x, lane = tid & 63, wave = tid >> 6;   // 0..7
  int wg = wave >> 1, wv = wave & 1;      // wave -> 64g x 64v quadrant
  int rsel = lane & 15, hi = lane >> 4;

  f32x4 acc[4][4];
  #pragma unroll
  for (int m = 0; m < 4; ++m)
    #pragma unroll
    for (int n = 0; n < 4; ++n) acc[m][n] = (f32x4){0.f, 0.f, 0.f, 0.f};

  // staging: chunk c: row c>>2, phys slot c&3; global segment = slot ^ ((row>>1)&3)
  int r1 = tid >> 2, s1 = tid & 3;
  int seg = (s1 ^ ((r1 >> 1) & 3)) * 8;
  const unsigned short* gA1 = Ab + (size_t)(g0 + r1) * 512 + seg;
  const unsigned short* gA2 = Ab + (size_t)(g0 + r1 + 128) * 512 + seg;
  int vr = v0 + r1; if (vr > V - 1) vr = V - 1;
  const unsigned short* gB1 = Bb + (size_t)vr * 512 + seg;

  int wofs = wave * 512;   // shorts; 64 lanes x 16B = 1KB per wave

#define L_STAGE(bi)                                                        \
  do {                                                                     \
    unsigned short* aB = (unsigned short*)(smem + (bi) * 16384);           \
    unsigned short* bB = (unsigned short*)(smem + 32768 + (bi) * 8192);    \
    gload_lds16(gA1, aB + wofs);                                           \
    gload_lds16(gA2, aB + 4096 + wofs);                                    \
    gload_lds16(gB1, bB + wofs);                                           \
    gA1 += 32; gA2 += 32; gB1 += 32;                                       \
  } while (0)

  L_STAGE(0);
  L_STAGE(1);

  int sl = (rsel >> 1) & 3;   // read-side swizzle term
  for (int kt = 0; kt < 16; ++kt) {
    __builtin_amdgcn_sched_barrier(0);
    if (kt < 15) asm volatile("s_waitcnt vmcnt(3)" ::: "memory");
    else         asm volatile("s_waitcnt vmcnt(0)" ::: "memory");
    __builtin_amdgcn_sched_barrier(0);
    __builtin_amdgcn_s_barrier();       // stage kt complete for all waves
    __builtin_amdgcn_sched_barrier(0);

    const unsigned short* Ac = (const unsigned short*)(smem + (kt & 1) * 16384);
    const unsigned short* Bc = (const unsigned short*)(smem + 32768 + (kt & 1) * 8192);
    bf16x8 af[4], bfr[4];
    #pragma unroll
    for (int m = 0; m < 4; ++m)
      af[m] = *(const bf16x8*)(Ac + (wg * 64 + m * 16 + rsel) * 32 + ((hi ^ sl) * 8));
    #pragma unroll
    for (int n = 0; n < 4; ++n)
      bfr[n] = *(const bf16x8*)(Bc + (wv * 64 + n * 16 + rsel) * 32 + ((hi ^ sl) * 8));
    #pragma unroll
    for (int m = 0; m < 4; ++m)
      #pragma unroll
      for (int n = 0; n < 4; ++n)
        acc[m][n] = __builtin_amdgcn_mfma_f32_16x16x32_bf16(af[m], bfr[n], acc[m][n], 0, 0, 0);

    __builtin_amdgcn_sched_barrier(0);
    __builtin_amdgcn_s_barrier();       // buffer kt free for restage
    __builtin_amdgcn_sched_barrier(0);
    if (kt + 2 < 16) L_STAGE(kt & 1);   // stage t+2 into the buffer just freed
  }
#undef L_STAGE

  // Epilogue: LDS transpose -> float4 coalesced stores, 4 passes (g quarters).
  __syncthreads();
  float* ebuf = (float*)smem;   // [64][132] = 33792 B <= 49152
  #pragma unroll
  for (int p = 0; p < 4; ++p) {
    if (p) __syncthreads();
    if (wg == p) {
      #pragma unroll
      for (int m = 0; m < 4; ++m)
        #pragma unroll
        for (int i = 0; i < 4; ++i) {
          int lr = m * 16 + hi * 4 + i;
          #pragma unroll
          for (int n = 0; n < 4; ++n)
            ebuf[lr * 132 + wv * 64 + n * 16 + rsel] = acc[m][n][i];
        }
    }
    __syncthreads();
    #pragma unroll
    for (int j = 0; j < 4; ++j) {
      int f = tid + j * 512;                 // 0..2047: 64 rows x 32 float4
      int lr = f >> 5, c4 = (f & 31) * 4;
      int g = g0 + p * 64 + lr;
      int b = g >> 5, lt = g & 31;
      int v = v0 + c4;
      if (lt < S && v < V) {
        float4 val = *(const float4*)(ebuf + lr * 132 + c4);
        float4 cb4 = *(const float4*)(cbase + (size_t)b * V + v);
        float4 o;
        o.x = val.x + cb4.x; o.y = val.y + cb4.y;
        o.z = val.z + cb4.z; o.w = val.w + cb4.w;
        *(float4*)(out + ((size_t)b * S + lt) * V + v) = o;
      }
    }
  }
}

// ---------------------------------------------------------------------------
extern "C" void kernel_launch(void* const* d_in, const int* in_sizes, int n_in,
                              void* d_out, int out_size, void* d_ws, size_t ws_size,
                              hipStream_t stream) {
  const float* features = (const float*)d_in[0];
  const int*   captions = (const int*)d_in[1];
  const float* embed_W  = (const float*)d_in[3];
  const float* W1   = (const float*)d_in[4];
  const float* b1   = (const float*)d_in[5];
  const float* cw1  = (const float*)d_in[6];
  const float* cb1  = (const float*)d_in[7];
  const float* cw2  = (const float*)d_in[8];
  const float* cb2  = (const float*)d_in[9];
  const float* Wenc = (const float*)d_in[10];
  const float* benc = (const float*)d_in[11];
  const float* Wp   = (const float*)d_in[14];
  const float* W2   = (const float*)d_in[16];
  const float* b2   = (const float*)d_in[17];
  float* out = (float*)d_out;

  float* ws = (float*)d_ws;
  float* wv       = ws;                 // 1024
  float* c0       = ws + 1024;          // 16
  unsigned short* enc_meanb = (unsigned short*)(ws + 1040);  // 65536 bf16
  unsigned short* ctxb = (unsigned short*)(ws + 66576);      // 65536 bf16
  float* xA       = ws + 164880;        // 1048576 (x1; x3b overlays later)
  float* xB       = ws + 1213456;       // 1048576 (x2)
  float* cbase    = ws + 2262032;       // 1920000
  unsigned short* x3b  = (unsigned short*)xA;             // 1048576 bf16 (xA dead)
  unsigned short* Xc   = (unsigned short*)(ws + 4359184); // 7340032 bf16
  unsigned short* wbuf = (unsigned short*)(ws + 8029200); // 3670016 bf16
  unsigned short* W2d  = (unsigned short*)(ws + 9864208); // 15360000 bf16
  unsigned short* Xe  = Xc;                  // 1048576 bf16 (pre-im2col)
  unsigned short* w1b = Xc + 1048576;        // 786432 bf16 (full W1)
  // end: 17,544,208 floats = 70.2 MB (unchanged)

  hipLaunchKernelGGL(k_cvt_w2d,  dim3(15000),   dim3(256), 0, stream, W2, W2d);
  hipLaunchKernelGGL(k_wv,       dim3(16),      dim3(256), 0, stream, Wenc, Wp, benc, wv, c0);
  hipLaunchKernelGGL(k_mean_ctx, dim3(B),       dim3(256), 0, stream, features, wv, c0, enc_meanb, ctxb);

  // x1 = b1 + [enc_mean||emb] @ W1ᵀ  (fused MFMA, K=1536)
  hipLaunchKernelGGL(k_gather_emb, dim3(2048),  dim3(256), 0, stream, embed_W, captions, Xe);
  hipLaunchKernelGGL(k_cvt_w1,     dim3(512),   dim3(256), 0, stream, W1, w1b);
  hipLaunchKernelGGL(k_x1f_mfma,   dim3(8, 32), dim3(256), 0, stream, enc_meanb, Xe, w1b, b1, xA);

  // conv layer 1 (GEMM+GLU fused; writes gated+res fp32 into xB)
  hipLaunchKernelGGL(k_cvt_wconv,   dim3(1024),   dim3(256), 0, stream, cw1, wbuf);
  hipLaunchKernelGGL(k_im2col,      dim3(2048),   dim3(256), 0, stream, xA, Xc);
  hipLaunchKernelGGL(k_conv_glu<0>, dim3(16, 32), dim3(256), 0, stream, Xc, wbuf, cb1, xA, xB, (unsigned short*)nullptr);

  // conv layer 2 (writes bf16 x3 directly)
  hipLaunchKernelGGL(k_cvt_wconv,   dim3(1024),   dim3(256), 0, stream, cw2, wbuf);
  hipLaunchKernelGGL(k_im2col,      dim3(2048),   dim3(256), 0, stream, xB, Xc);
  hipLaunchKernelGGL(k_conv_glu<1>, dim3(16, 32), dim3(256), 0, stream, Xc, wbuf, cb2, xB, (float*)nullptr, x3b);

  hipLaunchKernelGGL(k_cbase_mfma, dim3(235),   dim3(256), 0, stream, ctxb, W2, b2, cbase);
  hipLaunchKernelGGL(k_logits_mfma, dim3(1880), dim3(512), 0, stream, x3b, W2d, cbase, out);
}